// Round 16
// baseline (79.309 us; speedup 1.0000x reference)
//
#include <hip/hip_runtime.h>

#define KS    13
#define HALF  6
#define TY    32              // output rows per strip
#define SEG   512             // output cols per block (column split: 2x blocks)
#define SW    (SEG + 16)      // 528 staged floats/row: 8 halo + 512 + 8
#define NGR   (SW / 4)        // 132 granules/row
#define NITER (TY + 12)       // 44 staged rows
#define NK    (NITER / 2)     // 22 iterations, 2 rows per barrier
#define IMG_H 1024
#define IMG_W 1024

__device__ __forceinline__ int reflect_idx(int i, int n) {
    if (i < 0) i = -i;
    if (i >= n) i = 2 * n - 2 - i;
    return i;
}

struct Ctx {
    const float* xin;
    float*       o;
    float        g[KS];
    int          t;        // 0..127; output cols c0+4t..+3
    int          c0;       // block's first output col
    int          r0;       // strip's first output row
};

// Load one granule (4 floats), reflecting at image columns when out of range.
__device__ __forceinline__ float4 load_gran(const float* rowp, int gc0) {
    if (gc0 >= 0 && gc0 <= IMG_W - 4)
        return *reinterpret_cast<const float4*>(rowp + gc0);
    float4 v;
    v.x = rowp[reflect_idx(gc0 + 0, IMG_W)];
    v.y = rowp[reflect_idx(gc0 + 1, IMG_W)];
    v.z = rowp[reflect_idx(gc0 + 2, IMG_W)];
    v.w = rowp[reflect_idx(gc0 + 3, IMG_W)];
    return v;
}

// H-filter one staged row: thread t reads local floats 4t..4t+19 (granules
// t..t+4; consecutive-lane b128 -> conflict-free), 13 taps x 4 cols.
// Branch-free for ALL threads: column halo is pre-staged.
__device__ __forceinline__ float4 h_filter(const float* srow, const Ctx& cx) {
    float f[20];
    #pragma unroll
    for (int k = 0; k < 5; ++k) {
        float4 v = *reinterpret_cast<const float4*>(srow + 4 * cx.t + 4 * k);
        f[4*k+0] = v.x; f[4*k+1] = v.y; f[4*k+2] = v.z; f[4*k+3] = v.w;
    }
    float4 h = make_float4(0.f, 0.f, 0.f, 0.f);
    #pragma unroll
    for (int j = 0; j < KS; ++j) {
        h.x += cx.g[j] * f[2 + j];
        h.y += cx.g[j] * f[3 + j];
        h.z += cx.g[j] * f[4 + j];
        h.w += cx.g[j] * f[5 + j];
    }
    return h;
}

// Iteration k (= outer*7 + U): commit staged rows 2k,2k+1 to the (k&1) LDS pair,
// prefetch rows 2k+2,2k+3 (in flight across barrier + compute, T14), ONE
// barrier, H-filter both into window slots (2U)%14,(2U+1)%14, V-filter -> 2
// output rows. Window indices compile-time (rule #20). WAR safety: iter k's
// reads precede barrier_{k+1}; iter k+2's rewrites follow it (R13 proof).
template<int U>
__device__ __forceinline__ void body2(int outer, const Ctx& cx, float (*s)[SW],
                                      float4 (&w)[14],
                                      float4& cA0, float4& cB0,
                                      float4& cA1, float4& cB1)
{
    const int k = outer * 7 + U;
    if (k >= NK) return;                 // block-uniform guard (barrier-safe)
    const int n0 = 2 * k;
    const int bp = (k & 1) * 2;
    const bool hasB = cx.t < NGR - 128;  // threads 0..3 also stage granules 128..131

    // commit staged rows to the LDS pair
    *reinterpret_cast<float4*>(&s[bp + 0][4 * cx.t]) = cA0;
    *reinterpret_cast<float4*>(&s[bp + 1][4 * cx.t]) = cA1;
    if (hasB) {
        *reinterpret_cast<float4*>(&s[bp + 0][512 + 4 * cx.t]) = cB0;
        *reinterpret_cast<float4*>(&s[bp + 1][512 + 4 * cx.t]) = cB1;
    }

    // prefetch next row pair: rows n0+2,n0+3 = input rows r0+n0-4, r0+n0-3
    if (k + 1 < NK) {
        const float* ra = cx.xin + (size_t)reflect_idx(cx.r0 + n0 - 4, IMG_H) * IMG_W;
        const float* rb = cx.xin + (size_t)reflect_idx(cx.r0 + n0 - 3, IMG_H) * IMG_W;
        const int gA = cx.c0 - 8 + 4 * cx.t;
        cA0 = load_gran(ra, gA);
        cA1 = load_gran(rb, gA);
        if (hasB) {
            const int gB = cx.c0 - 8 + 4 * (128 + cx.t);
            cB0 = load_gran(ra, gB);
            cB1 = load_gran(rb, gB);
        }
    }
    __syncthreads();

    // two H-filters into the rolling 14-slot window
    w[(2 * U) % 14]     = h_filter(s[bp + 0], cx);
    w[(2 * U + 1) % 14] = h_filter(s[bp + 1], cx);

    // two V-filters -> output rows r0+n0-12, r0+n0-11
    if (n0 >= 12) {
        float4 a0 = make_float4(0.f, 0.f, 0.f, 0.f);
        float4 a1 = make_float4(0.f, 0.f, 0.f, 0.f);
        #pragma unroll
        for (int j = 0; j < KS; ++j) {
            const float4 v0 = w[(2 * U + 2 + j) % 14];
            const float4 v1 = w[(2 * U + 3 + j) % 14];
            a0.x += cx.g[j] * v0.x;  a1.x += cx.g[j] * v1.x;
            a0.y += cx.g[j] * v0.y;  a1.y += cx.g[j] * v1.y;
            a0.z += cx.g[j] * v0.z;  a1.z += cx.g[j] * v1.z;
            a0.w += cx.g[j] * v0.w;  a1.w += cx.g[j] * v1.w;
        }
        float* d0 = cx.o + (size_t)(cx.r0 + n0 - 12) * IMG_W + cx.c0 + 4 * cx.t;
        float* d1 = cx.o + (size_t)(cx.r0 + n0 - 11) * IMG_W + cx.c0 + 4 * cx.t;
        *reinterpret_cast<float4*>(d0) = a0;
        *reinterpret_cast<float4*>(d1) = a1;
    }
}

// 128-thread (2-wave) blocks: 2048 blocks = 8 resident/CU -> 8 independent
// half-width convoy streams (vs 4 four-wave streams in R15).
// No launch-bounds min-waves (R2: VGPR cap -> spill). Expect ~110 VGPR.
__global__ __launch_bounds__(128) void gauss_blur_stream(
    const float* __restrict__ x, const float* __restrict__ k2d,
    float* __restrict__ out)
{
    __shared__ float s[4][SW];   // 8448 B: two ping-pong row pairs

    Ctx cx;
    cx.t  = threadIdx.x;
    cx.c0 = blockIdx.x * SEG;
    cx.r0 = blockIdx.y * TY;
    const int img = blockIdx.z;
    cx.xin = x + (size_t)img * IMG_H * IMG_W;
    cx.o   = out + (size_t)img * IMG_H * IMG_W;

    // 1D taps: k2d = outer(g,g) exactly, g[i] = k2d[i][6]/sqrt(k2d[6][6])
    {
        float c   = k2d[HALF * KS + HALF];
        float inv = 1.0f / sqrtf(c);
        #pragma unroll
        for (int j = 0; j < KS; ++j) cx.g[j] = k2d[j * KS + HALF] * inv;
    }

    // preload rows 0,1 (input rows r0-6, r0-5)
    const bool hasB = cx.t < NGR - 128;
    const int  gA   = cx.c0 - 8 + 4 * cx.t;
    const int  gB   = cx.c0 - 8 + 4 * (128 + cx.t);
    const float* ra = cx.xin + (size_t)reflect_idx(cx.r0 - 6, IMG_H) * IMG_W;
    const float* rb = cx.xin + (size_t)reflect_idx(cx.r0 - 5, IMG_H) * IMG_W;
    float4 cA0 = load_gran(ra, gA);
    float4 cA1 = load_gran(rb, gA);
    float4 cB0 = hasB ? load_gran(ra, gB) : make_float4(0,0,0,0);
    float4 cB1 = hasB ? load_gran(rb, gB) : make_float4(0,0,0,0);

    float4 w[14];
    for (int outer = 0; outer < 4; ++outer) {   // 4*7 = 28 bodies, guard k<22
        body2<0>(outer, cx, s, w, cA0, cB0, cA1, cB1);
        body2<1>(outer, cx, s, w, cA0, cB0, cA1, cB1);
        body2<2>(outer, cx, s, w, cA0, cB0, cA1, cB1);
        body2<3>(outer, cx, s, w, cA0, cB0, cA1, cB1);
        body2<4>(outer, cx, s, w, cA0, cB0, cA1, cB1);
        body2<5>(outer, cx, s, w, cA0, cB0, cA1, cB1);
        body2<6>(outer, cx, s, w, cA0, cB0, cA1, cB1);
    }
}

extern "C" void kernel_launch(void* const* d_in, const int* in_sizes, int n_in,
                              void* d_out, int out_size, void* d_ws, size_t ws_size,
                              hipStream_t stream) {
    const float* x   = (const float*)d_in[0];
    const float* k2d = (const float*)d_in[1];
    float*       out = (float*)d_out;

    dim3 grid(IMG_W / SEG, IMG_H / TY, 32);   // 2 x 32 x 32 = 2048 blocks
    gauss_blur_stream<<<grid, 128, 0, stream>>>(x, k2d, out);
}

// Round 17
// 54.718 us; speedup vs baseline: 1.4494x; 1.4494x over previous
//
#include <hip/hip_runtime.h>

#define KS    13
#define HALF  6
#define TY    32              // output rows per strip (R13 geometry — best measured)
#define NITER (TY + 12)       // 44 staged rows
#define NK    (NITER / 2)     // 22 iterations, 2 rows per barrier
#define IMG_H 1024
#define IMG_W 1024

__device__ __forceinline__ int reflect_idx(int i, int n) {
    if (i < 0) i = -i;
    if (i >= n) i = 2 * n - 2 - i;
    return i;
}

// Raw barrier WITHOUT the vmcnt(0) drain __syncthreads embeds:
//  - lgkmcnt(0): our ds_writes visible to other waves before they cross
//  - s_barrier: workgroup sync
//  - sched_barrier(0): pin ds_reads below (rule #18: compiler hoists past asm waits)
// Prefetch global_loads (into registers) stay IN FLIGHT across this barrier;
// the compiler waits them only at next iteration's ds_write (reg dependency).
__device__ __forceinline__ void lds_barrier() {
    asm volatile("s_waitcnt lgkmcnt(0)" ::: "memory");
    __builtin_amdgcn_sched_barrier(0);
    __builtin_amdgcn_s_barrier();
    __builtin_amdgcn_sched_barrier(0);
    asm volatile("" ::: "memory");
}

struct Ctx {
    const float* xin;
    float*       o;
    float        g[KS];
    int          t;        // thread's column granule: cols 4t..4t+3
    int          r0;       // strip's first output row
    bool         interior; // 2 <= t <= 253 : LDS window read needs no column reflect
};

// H-filter one staged row from LDS: 20-float window -> 4 outputs.
__device__ __forceinline__ float4 h_filter(const float* srow, const Ctx& cx) {
    float f[20];
    if (cx.interior) {
        #pragma unroll
        for (int k = 0; k < 5; ++k) {
            float4 v = *reinterpret_cast<const float4*>(srow + 4 * cx.t - 8 + 4 * k);
            f[4*k+0] = v.x; f[4*k+1] = v.y; f[4*k+2] = v.z; f[4*k+3] = v.w;
        }
    } else {
        #pragma unroll
        for (int k = 0; k < 20; ++k)
            f[k] = srow[reflect_idx(4 * cx.t - 8 + k, IMG_W)];
    }
    float4 h = make_float4(0.f, 0.f, 0.f, 0.f);
    #pragma unroll
    for (int j = 0; j < KS; ++j) {
        h.x += cx.g[j] * f[2 + j];
        h.y += cx.g[j] * f[3 + j];
        h.z += cx.g[j] * f[4 + j];
        h.w += cx.g[j] * f[5 + j];
    }
    return h;
}

// Iteration k (= outer*7 + U): stages raw rows 2k,2k+1 into the (k&1) LDS pair,
// prefetches rows 2k+2,2k+3 (now genuinely in flight across the raw barrier),
// ONE barrier, H-filters both into window slots (2U)%14,(2U+1)%14, then (k>=6)
// V-filters -> output rows r0+2k-12, r0+2k-11. Window indices compile-time
// (rule #20). WAR safety: iter k's reads precede its barrier_{k+1} (lgkmcnt(0)
// covers them); iter k+2's rewrites of this pair follow barrier_{k+1}.
template<int U>
__device__ __forceinline__ void body2(int outer, const Ctx& cx, float (*s)[IMG_W],
                                      float4 (&w)[14], float4& cur0, float4& cur1)
{
    const int k = outer * 7 + U;
    if (k >= NK) return;                 // block-uniform guard (barrier-safe)
    const int n0 = 2 * k;
    const int bp = (k & 1) * 2;          // LDS buffer pair

    // commit staged rows; then issue next pair's loads
    *reinterpret_cast<float4*>(&s[bp + 0][4 * cx.t]) = cur0;
    *reinterpret_cast<float4*>(&s[bp + 1][4 * cx.t]) = cur1;
    if (k + 1 < NK) {
        const int ra = reflect_idx(cx.r0 + n0 - 4, IMG_H);  // row n0+2
        const int rb = reflect_idx(cx.r0 + n0 - 3, IMG_H);  // row n0+3
        cur0 = *reinterpret_cast<const float4*>(cx.xin + (size_t)ra * IMG_W + 4 * cx.t);
        cur1 = *reinterpret_cast<const float4*>(cx.xin + (size_t)rb * IMG_W + 4 * cx.t);
    }
    lds_barrier();

    // two H-filters into the rolling 14-slot window
    w[(2 * U) % 14]     = h_filter(s[bp + 0], cx);
    w[(2 * U + 1) % 14] = h_filter(s[bp + 1], cx);

    // two V-filters -> output rows r0+n0-12, r0+n0-11
    if (n0 >= 12) {
        float4 a0 = make_float4(0.f, 0.f, 0.f, 0.f);
        float4 a1 = make_float4(0.f, 0.f, 0.f, 0.f);
        #pragma unroll
        for (int j = 0; j < KS; ++j) {
            const float4 v0 = w[(2 * U + 2 + j) % 14];
            const float4 v1 = w[(2 * U + 3 + j) % 14];
            a0.x += cx.g[j] * v0.x;  a1.x += cx.g[j] * v1.x;
            a0.y += cx.g[j] * v0.y;  a1.y += cx.g[j] * v1.y;
            a0.z += cx.g[j] * v0.z;  a1.z += cx.g[j] * v1.z;
            a0.w += cx.g[j] * v0.w;  a1.w += cx.g[j] * v1.w;
        }
        *reinterpret_cast<float4*>(cx.o + (size_t)(cx.r0 + n0 - 12) * IMG_W + 4 * cx.t) = a0;
        *reinterpret_cast<float4*>(cx.o + (size_t)(cx.r0 + n0 - 11) * IMG_W + 4 * cx.t) = a1;
    }
}

// No launch-bounds min-waves (R2: VGPR cap -> spill). Expect ~100 VGPR.
__global__ __launch_bounds__(256) void gauss_blur_stream(
    const float* __restrict__ x, const float* __restrict__ k2d,
    float* __restrict__ out)
{
    __shared__ float s[4][IMG_W];   // 16384 B: two ping-pong row PAIRS

    Ctx cx;
    cx.t  = threadIdx.x;
    cx.r0 = blockIdx.x * TY;
    const int img = blockIdx.y;
    cx.xin = x + (size_t)img * IMG_H * IMG_W;
    cx.o   = out + (size_t)img * IMG_H * IMG_W;
    cx.interior = (cx.t >= 2) && (cx.t <= 253);

    // 1D taps: k2d = outer(g,g) exactly, g[i] = k2d[i][6]/sqrt(k2d[6][6])
    {
        float c   = k2d[HALF * KS + HALF];
        float inv = 1.0f / sqrtf(c);
        #pragma unroll
        for (int j = 0; j < KS; ++j) cx.g[j] = k2d[j * KS + HALF] * inv;
    }

    float4 w[14];
    // preload rows n=0,1 (input rows r0-6, r0-5, reflected)
    float4 cur0 = *reinterpret_cast<const float4*>(
        cx.xin + (size_t)reflect_idx(cx.r0 - 6, IMG_H) * IMG_W + 4 * cx.t);
    float4 cur1 = *reinterpret_cast<const float4*>(
        cx.xin + (size_t)reflect_idx(cx.r0 - 5, IMG_H) * IMG_W + 4 * cx.t);

    for (int outer = 0; outer < 4; ++outer) {   // 4*7 = 28 bodies, guard k<22
        body2<0>(outer, cx, s, w, cur0, cur1);
        body2<1>(outer, cx, s, w, cur0, cur1);
        body2<2>(outer, cx, s, w, cur0, cur1);
        body2<3>(outer, cx, s, w, cur0, cur1);
        body2<4>(outer, cx, s, w, cur0, cur1);
        body2<5>(outer, cx, s, w, cur0, cur1);
        body2<6>(outer, cx, s, w, cur0, cur1);
    }
}

extern "C" void kernel_launch(void* const* d_in, const int* in_sizes, int n_in,
                              void* d_out, int out_size, void* d_ws, size_t ws_size,
                              hipStream_t stream) {
    const float* x   = (const float*)d_in[0];
    const float* k2d = (const float*)d_in[1];
    float*       out = (float*)d_out;

    dim3 grid(IMG_H / TY, 32);   // 32 strips x 32 images = 1024 blocks
    gauss_blur_stream<<<grid, 256, 0, stream>>>(x, k2d, out);
}